// Round 6
// baseline (252.661 us; speedup 1.0000x reference)
//
#include <hip/hip_runtime.h>

typedef float v2f __attribute__((ext_vector_type(2)));

#define IMG_W 512
#define IMG_H 512
#define RH    32            // output rows per wave
#define BW    128           // output cols per wave (2 cols/lane)
#define NW    4             // independent waves per workgroup
#define KS    11
#define KR    5
#define OFFP  9             // left pad in PAIRS; odd => 16B-aligned b128 window
#define LROWP (OFFP + BW + OFFP)     // 146 {a,b} pairs per row buffer
#define ROWS  (RH + 2 * KR)          // 42 input rows per strip

// RAW prefetch; OOB lanes/rows hold -1.0f -> fmaf(v,0.5,0.5) = 0.0 = conv pad.
struct Pf { float ax, ay, bx, by, lx, lb, rx, rb; };

// ROUND 6: I-cache theory. Rounds 1/3/4/5 (all ~20-24 KB fully-unrolled
// 11-phase bodies) pinned at 126-134 us / 19% occupancy / 44% VALUBusy
// regardless of grid, WG shape, barriers, prefetch => instruction-fetch
// thrash, not data-side limits. This version: DYNAMIC 42-iter loop, ONE
// phase per body (~2.5 KB). Ring keeps static indices via line-buffer
// shift (slot s <- s+1, new row -> slot 10, vertical reads 0..10 with
// fixed weights). Single LDS buffer/wave (per-wave LDS is in-order).
__global__ __launch_bounds__(256, 2)
void ssim_main(const float* __restrict__ xhat,
               const float* __restrict__ x,
               const float* __restrict__ kern,
               float* __restrict__ accum)
{
    __shared__ __align__(16) float lds[NW][2 * LROWP];  // 4.7 KB/WG

    const int lane  = threadIdx.x & 63;
    const int wv    = threadIdx.x >> 6;         // band index (0..3)
    const int strip = blockIdx.x & 15;          // 16 strips of 32 rows
    const int img   = blockIdx.x >> 4;
    const int base  = wv * BW;
    const int R0    = strip * RH;
    const float* xp = x    + (size_t)img * (IMG_W * IMG_H);
    const float* hp = xhat + (size_t)img * (IMG_W * IMG_H);

    // separable 1D weights from the rank-1 2D kernel (wave-uniform -> SGPRs)
    float g[KS];
    {
        const float inv = rsqrtf(kern[5 * KS + 5]);
        #pragma unroll
        for (int i = 0; i < KS; ++i) g[i] = kern[5 * KS + i] * inv;
    }

    const int  c0   = lane << 1;
    const bool lh   = lane < KR;
    const bool rhn  = lane >= 64 - KR;
    const int  lcol = base - KR + lane;
    const int  rcol = base + BW + (lane - (64 - KR));
    const int  lidx = OFFP - KR + lane;
    const int  ridx = OFFP + BW + (lane - (64 - KR));

    float* buf = lds[wv];

    auto load_raw = [&](int rr) -> Pf {
        Pf p = {-1.f,-1.f,-1.f,-1.f,-1.f,-1.f,-1.f,-1.f};
        const int ri = R0 - KR + rr;
        if (ri >= 0 && ri < IMG_H) {
            const size_t ro = (size_t)ri * IMG_W;
            const float2 vx = *(const float2*)(xp + ro + base + c0);
            const float2 vh = *(const float2*)(hp + ro + base + c0);
            p.ax = vx.x;  p.ay = vx.y;
            p.bx = vh.x;  p.by = vh.y;
            if (lh && lcol >= 0)    { p.lx = xp[ro + lcol]; p.lb = hp[ro + lcol]; }
            if (rhn && rcol < IMG_W){ p.rx = xp[ro + rcol]; p.rb = hp[ro + rcol]; }
        }
        return p;
    };

    // line-buffer ring: slot s holds h-fields of input row (rr-10+s)
    v2f h01r[KS][2];   // {sum a, sum b} per col
    v2f h23r[KS][2];   // {sum a^2, sum b^2} per col
    v2f h4r [KS];      // {sum ab col0, sum ab col1}
    float acc = 0.f;
    const float C1 = 1e-4f, C2 = 9e-4f;

    Pf cur = load_raw(0);

    #pragma unroll 1
    for (int rr = 0; rr < ROWS; ++rr) {
        // ---- stage row rr: raw -> (v+1)/2, interleaved {a,b} pairs ----
        *(float2*)&buf[2 * (OFFP + c0)] =
            make_float2(fmaf(cur.ax, 0.5f, 0.5f), fmaf(cur.bx, 0.5f, 0.5f));
        *(float2*)&buf[2 * (OFFP + c0) + 2] =
            make_float2(fmaf(cur.ay, 0.5f, 0.5f), fmaf(cur.by, 0.5f, 0.5f));
        if (lh)  *(float2*)&buf[2 * lidx] =
            make_float2(fmaf(cur.lx, 0.5f, 0.5f), fmaf(cur.lb, 0.5f, 0.5f));
        if (rhn) *(float2*)&buf[2 * ridx] =
            make_float2(fmaf(cur.rx, 0.5f, 0.5f), fmaf(cur.rb, 0.5f, 0.5f));

        // ---- issue raw prefetch of row rr+1 (vmcnt in flight over LDS) ----
        const Pf nxt = load_raw(rr + 1);   // ri-guard handles rr+1==ROWS

        // compiler-only ordering fence; per-wave LDS executes in order
        __asm__ __volatile__("" ::: "memory");

        // ---- horizontal pass: 6x ds_read_b128 window ----
        const float4* q = (const float4*)buf;
        float4 w[6];
        #pragma unroll
        for (int j = 0; j < 6; ++j) w[j] = q[lane + 2 + j];

        v2f h01[2] = {{0.f,0.f},{0.f,0.f}};
        v2f h23[2] = {{0.f,0.f},{0.f,0.f}};
        v2f h4v    = {0.f, 0.f};
        #pragma unroll
        for (int t = 0; t < KS + 1; ++t) {
            v2f ab;
            ab.x = (t & 1) ? w[t >> 1].z : w[t >> 1].x;
            ab.y = (t & 1) ? w[t >> 1].w : w[t >> 1].y;
            const v2f  ab2 = ab * ab;
            const float pab = ab.x * ab.y;
            if (t < KS) {                 // tap for col 0
                const v2f wv2 = {g[t], g[t]};
                h01[0] = __builtin_elementwise_fma(ab,  wv2, h01[0]);
                h23[0] = __builtin_elementwise_fma(ab2, wv2, h23[0]);
                h4v.x  = fmaf(pab, g[t], h4v.x);
            }
            if (t > 0) {                  // tap for col 1
                const v2f wv2 = {g[t - 1], g[t - 1]};
                h01[1] = __builtin_elementwise_fma(ab,  wv2, h01[1]);
                h23[1] = __builtin_elementwise_fma(ab2, wv2, h23[1]);
                h4v.y  = fmaf(pab, g[t - 1], h4v.y);
            }
        }

        // ---- ring shift (static indices; pk_mov-able) + insert at slot 10 ----
        #pragma unroll
        for (int s = 0; s < KS - 1; ++s) {
            h01r[s][0] = h01r[s + 1][0];  h01r[s][1] = h01r[s + 1][1];
            h23r[s][0] = h23r[s + 1][0];  h23r[s][1] = h23r[s + 1][1];
            h4r [s]    = h4r [s + 1];
        }
        h01r[KS - 1][0] = h01[0];  h01r[KS - 1][1] = h01[1];
        h23r[KS - 1][0] = h23[0];  h23r[KS - 1][1] = h23[1];
        h4r [KS - 1]    = h4v;

        // ---- vertical pass + SSIM: slot s = row rr-10+s, fixed weights ----
        if (rr >= 2 * KR) {
            v2f v01[2] = {{0.f,0.f},{0.f,0.f}};
            v2f v23[2] = {{0.f,0.f},{0.f,0.f}};
            v2f v4     = {0.f, 0.f};
            #pragma unroll
            for (int t = 0; t < KS; ++t) {
                const v2f wv2 = {g[t], g[t]};
                v01[0] = __builtin_elementwise_fma(h01r[t][0], wv2, v01[0]);
                v01[1] = __builtin_elementwise_fma(h01r[t][1], wv2, v01[1]);
                v23[0] = __builtin_elementwise_fma(h23r[t][0], wv2, v23[0]);
                v23[1] = __builtin_elementwise_fma(h23r[t][1], wv2, v23[1]);
                v4     = __builtin_elementwise_fma(h4r[t],     wv2, v4);
            }
            #pragma unroll
            for (int c = 0; c < 2; ++c) {
                const float mux  = v01[c].x, muy = v01[c].y;
                const float mux2 = mux * mux;
                const float muy2 = muy * muy;
                const float muxy = mux * muy;
                const float sx   = v23[c].x - mux2;
                const float sy   = v23[c].y - muy2;
                const float sxy  = ((c == 0) ? v4.x : v4.y) - muxy;
                const float num  = (2.f * muxy + C1) * (2.f * sxy + C2);
                const float den  = (mux2 + muy2 + C1) * (sx + sy + C2);
                acc = fmaf(num, __builtin_amdgcn_rcpf(den + 1e-8f), acc);
            }
        }

        cur = nxt;
    }

    // per-wave shuffle reduce, one atomic per wave
    #pragma unroll
    for (int o = 32; o > 0; o >>= 1) acc += __shfl_down(acc, o, 64);
    if (lane == 0) atomicAdd(accum, acc);
}

__global__ void ssim_final(const float* __restrict__ accum,
                           float* __restrict__ out)
{
    out[0] = 1.0f - accum[0] * (1.0f / (64.0f * 512.0f * 512.0f));
}

extern "C" void kernel_launch(void* const* d_in, const int* in_sizes, int n_in,
                              void* d_out, int out_size, void* d_ws, size_t ws_size,
                              hipStream_t stream) {
    const float* xhat = (const float*)d_in[0];
    const float* xin  = (const float*)d_in[1];
    const float* kern = (const float*)d_in[2];
    float* out = (float*)d_out;
    float* ws  = (float*)d_ws;

    const int nimg = in_sizes[0] / (IMG_W * IMG_H);   // 64
    const int nblk = nimg * (IMG_H / RH);             // 1024 WGs x 4 waves

    hipMemsetAsync(ws, 0, sizeof(float), stream);
    ssim_main<<<nblk, 64 * NW, 0, stream>>>(xhat, xin, kern, ws);
    ssim_final<<<1, 1, 0, stream>>>(ws, out);
}